// Round 2
// baseline (339.524 us; speedup 1.0000x reference)
//
#include <hip/hip_runtime.h>

// Problem constants (from reference setup_inputs)
#define BB 2048
#define TT 16
#define RR 2048
#define NPAIR (TT - 1)

__device__ __forceinline__ float log_sigmoid(float x) {
    // log(sigmoid(x)) = min(x,0) - log1p(exp(-|x|))  (numerically stable)
    return fminf(x, 0.0f) - log1pf(expf(-fabsf(x)));
}

// ---------------------------------------------------------------------------
// Kernel A: BCE-with-logits (pos_weight=2) masked mean over [B,T]
// ws[0] += sum(bce * vm);  ws[1] += sum(vm)
// ---------------------------------------------------------------------------
__global__ void class_loss_kernel(const float* __restrict__ pred,
                                  const int* __restrict__ targets,
                                  const int* __restrict__ vm,
                                  float* __restrict__ ws) {
    int tid = blockIdx.x * blockDim.x + threadIdx.x;
    int stride = gridDim.x * blockDim.x;
    float bce_sum = 0.f, vm_sum = 0.f;
    for (int i = tid; i < BB * TT; i += stride) {
        float x = pred[i];
        float y = (float)targets[i];
        float v = (float)vm[i];
        float bce = -(2.0f * y * log_sigmoid(x) + (1.0f - y) * log_sigmoid(-x));
        bce_sum += bce * v;
        vm_sum += v;
    }
    // wave (64-lane) reduce
    #pragma unroll
    for (int off = 32; off; off >>= 1) {
        bce_sum += __shfl_down(bce_sum, off);
        vm_sum  += __shfl_down(vm_sum, off);
    }
    __shared__ float s_b[8], s_v[8];
    int lane = threadIdx.x & 63, wave = threadIdx.x >> 6;
    if (lane == 0) { s_b[wave] = bce_sum; s_v[wave] = vm_sum; }
    __syncthreads();
    if (threadIdx.x == 0) {
        float b = 0.f, v = 0.f;
        int nw = blockDim.x >> 6;
        for (int w = 0; w < nw; ++w) { b += s_b[w]; v += s_v[w]; }
        atomicAdd(&ws[0], b);
        atomicAdd(&ws[1], v);
    }
}

// ---------------------------------------------------------------------------
// Kernel B: smoothness penalty sums.
// One block per b (512 threads, each owns one float4 slice of R=2048).
// S[p]     += pv[b,p] * sum_r relu(|rs[b,p+1,r]-rs[b,p,r]| - 0.2)^2   (raw, /R later)
// count[p] += pv[b,p]
// Loads only t-slices actually needed (uniform predicate per block).
// ---------------------------------------------------------------------------
__global__ __launch_bounds__(512)
void smooth_kernel(const float* __restrict__ rs,
                   const int* __restrict__ vm,
                   float* __restrict__ S,       // 15 floats
                   int* __restrict__ counts) {  // 15 ints
    int b = blockIdx.x;
    __shared__ int s_vm[TT];
    if (threadIdx.x < TT) s_vm[threadIdx.x] = vm[b * TT + threadIdx.x];
    __syncthreads();

    bool pv[NPAIR];
    #pragma unroll
    for (int p = 0; p < NPAIR; ++p) pv[p] = (s_vm[p] != 0) && (s_vm[p + 1] != 0);

    const float4* base = (const float4*)(rs + (size_t)b * TT * RR);
    const int r4 = threadIdx.x;  // 0..511 covers R/4

    float acc[NPAIR];
    #pragma unroll
    for (int p = 0; p < NPAIR; ++p) acc[p] = 0.f;

    float4 prev = make_float4(0.f, 0.f, 0.f, 0.f);
    #pragma unroll
    for (int t = 0; t < TT; ++t) {
        bool need = ((t > 0) && pv[t - 1]) || ((t < NPAIR) && pv[t]);  // uniform per block
        float4 cur = prev;
        if (need) cur = base[t * (RR / 4) + r4];
        if (t > 0 && pv[t - 1]) {
            float dx = fmaxf(fabsf(cur.x - prev.x) - 0.2f, 0.f);
            float dy = fmaxf(fabsf(cur.y - prev.y) - 0.2f, 0.f);
            float dz = fmaxf(fabsf(cur.z - prev.z) - 0.2f, 0.f);
            float dw = fmaxf(fabsf(cur.w - prev.w) - 0.2f, 0.f);
            acc[t - 1] += dx * dx + dy * dy + dz * dz + dw * dw;
        }
        prev = cur;
    }

    // block reduce the 15 accumulators (only valid pairs; pv uniform per block)
    __shared__ float s_acc[8][NPAIR];
    int lane = threadIdx.x & 63, wave = threadIdx.x >> 6;
    #pragma unroll
    for (int p = 0; p < NPAIR; ++p) {
        if (pv[p]) {
            float v = acc[p];
            #pragma unroll
            for (int off = 32; off; off >>= 1) v += __shfl_down(v, off);
            if (lane == 0) s_acc[wave][p] = v;
        }
    }
    __syncthreads();
    if (threadIdx.x < NPAIR) {
        int p = threadIdx.x;
        if (pv[p]) {
            float s = 0.f;
            #pragma unroll
            for (int w = 0; w < 8; ++w) s += s_acc[w][p];
            atomicAdd(&S[p], s);
            atomicAdd(&counts[p], 1);
        }
    }
}

// ---------------------------------------------------------------------------
// Kernel C: finalize — exact reference reduction order.
// ---------------------------------------------------------------------------
__global__ void finalize_kernel(const float* __restrict__ ws,
                                const int* __restrict__ counts,
                                float* __restrict__ out) {
    if (threadIdx.x != 0 || blockIdx.x != 0) return;
    float class_loss = ws[0] / fmaxf(ws[1], 1e-8f);
    float step_sum = 0.f;
    int num_steps = 0;
    for (int p = 0; p < NPAIR; ++p) {
        int c = counts[p];
        float pen_sum = ws[2 + p] / (float)RR;       // mean over regions folded in
        float step = pen_sum / (float)(c > 0 ? c : 1);
        step_sum += step;
        if (c > 0) ++num_steps;
    }
    float smooth = (num_steps > 0) ? (step_sum / (float)num_steps) : 0.f;
    out[0] = class_loss + 0.2f * smooth;
}

extern "C" void kernel_launch(void* const* d_in, const int* in_sizes, int n_in,
                              void* d_out, int out_size, void* d_ws, size_t ws_size,
                              hipStream_t stream) {
    const float* pred    = (const float*)d_in[0];  // [B,T,1] f32
    const float* rs      = (const float*)d_in[1];  // [B,T,R,1] f32
    const int*   targets = (const int*)d_in[2];    // [B,T] i32
    const int*   vmask   = (const int*)d_in[3];    // [B,T] i32
    float* out = (float*)d_out;
    float* ws  = (float*)d_ws;
    // ws layout: [0]=bce_sum, [1]=vm_sum, [2..16]=S[15], [17..31]=counts[15] (as int)
    hipMemsetAsync(d_ws, 0, 32 * sizeof(float), stream);

    class_loss_kernel<<<32, 256, 0, stream>>>(pred, targets, vmask, ws);
    smooth_kernel<<<BB, 512, 0, stream>>>(rs, vmask, ws + 2, (int*)(ws + 17));
    finalize_kernel<<<1, 64, 0, stream>>>(ws, (int*)(ws + 17), out);
}